// Round 7
// baseline (160.286 us; speedup 1.0000x reference)
//
#include <hip/hip_runtime.h>
#include <hip/hip_bf16.h>

// S4 layer: y = irfft( rfft(pad(u)) * (rfft(pad(K)) + D) )[:L]
// B=16, H=128, L=4096, N=64. All fp32.
// k_conv (this round): 512-thread radix-8 FFT4096 = 8^4. 8 float2/thread,
// 4 in-register fft8 stages + 3 LDS transposes each way. LDS buffer 4712
// float2 (36.8KB) -> 4 blocks/CU x 8 waves = 32 waves/CU (full occupancy).
// Transpose layouts addr = 589*dh + 74*da + 9*db + dc chosen so every
// wave LDS op has lane-digit strides {10,9,1} mod 16 -> uniform banks.
// Spectrum is scrambled: Z[k] at (thread t, reg k3), k = octrev3(t)+512*k3.
// k_khat writes the alpha/beta table pre-scrambled for that layout:
//   slot = octrev3(k&511) + 512*(k>>9)   (octrev3 is an involution).
// Spectral: Ypack[k] = alpha*Z[k] + beta*conj(Z[(4096-k)&4095]); self-
// paired bins k=0,2048 work automatically (full spectrum staged in LDS).
// launch_bounds (512,4): VGPR cap 128, natural ~60 -> no spill (R4/R5
// lesson: never force a cap below natural usage).
// ws: [0,4MiB) atR 128x4096 float2 ; [4MiB,12MiB) abt 128x4096 float4

#define PI_F 3.14159265358979323846f

__device__ __forceinline__ float2 cmulf(float2 a, float2 b) {
  return make_float2(a.x * b.x - a.y * b.y, a.x * b.y + a.y * b.x);
}
__device__ __forceinline__ void cmul_set(float2& v, float wr, float wi) {
  v = make_float2(v.x * wr - v.y * wi, v.x * wi + v.y * wr);
}
__device__ __forceinline__ int ad(int k) { return k + (k >> 4); }  // pad-17
__device__ __forceinline__ int orev(int x) {  // octal-digit reverse, 9 bits
  return ((x & 7) << 6) | (x & 56) | (x >> 6);
}

template <int SIGN>
__device__ __forceinline__ void bfly4(float2& a, float2& b, float2& c,
                                      float2& d) {
  float t0x = a.x + c.x, t0y = a.y + c.y;
  float t1x = a.x - c.x, t1y = a.y - c.y;
  float t2x = b.x + d.x, t2y = b.y + d.y;
  float t3x = b.x - d.x, t3y = b.y - d.y;
  a = make_float2(t0x + t2x, t0y + t2y);
  c = make_float2(t0x - t2x, t0y - t2y);
  if (SIGN < 0) {
    b = make_float2(t1x + t3y, t1y - t3x);
    d = make_float2(t1x - t3y, t1y + t3x);
  } else {
    b = make_float2(t1x - t3y, t1y + t3x);
    d = make_float2(t1x + t3y, t1y - t3x);
  }
}

// ---- 8-pt DFT in registers, natural in/out: V[k]=sum v[n] e^{SIGN 2pi i nk/8}
template <int SIGN>
__device__ __forceinline__ void fft8(float2 v[8]) {
  const float sg = (float)SIGN;
  const float R2 = 0.70710678118654752f;
  float2 e0 = make_float2(v[0].x + v[4].x, v[0].y + v[4].y);
  float2 o0 = make_float2(v[0].x - v[4].x, v[0].y - v[4].y);
  float2 e1 = make_float2(v[1].x + v[5].x, v[1].y + v[5].y);
  float2 o1 = make_float2(v[1].x - v[5].x, v[1].y - v[5].y);
  float2 e2 = make_float2(v[2].x + v[6].x, v[2].y + v[6].y);
  float2 o2 = make_float2(v[2].x - v[6].x, v[2].y - v[6].y);
  float2 e3 = make_float2(v[3].x + v[7].x, v[3].y + v[7].y);
  float2 o3 = make_float2(v[3].x - v[7].x, v[3].y - v[7].y);
  cmul_set(o1, R2, sg * R2);                 // W8^1
  o2 = make_float2(-sg * o2.y, sg * o2.x);   // W8^2
  cmul_set(o3, -R2, sg * R2);                // W8^3
  bfly4<SIGN>(e0, e1, e2, e3);
  bfly4<SIGN>(o0, o1, o2, o3);
  v[0] = e0; v[1] = o0; v[2] = e1; v[3] = o1;
  v[4] = e2; v[5] = o2; v[6] = e3; v[7] = o3;
}

// v[j] *= (c + i*s)^j, j=1..7 (log-depth power chain)
__device__ __forceinline__ void tw8(float2 v[8], float c, float s) {
  float2 p1 = make_float2(c, s);
  float2 p2 = cmulf(p1, p1);
  float2 p3 = cmulf(p1, p2);
  float2 p4 = cmulf(p2, p2);
  float2 p5 = cmulf(p2, p3);
  float2 p6 = cmulf(p3, p3);
  float2 p7 = cmulf(p3, p4);
  v[1] = cmulf(v[1], p1); v[2] = cmulf(v[2], p2);
  v[3] = cmulf(v[3], p3); v[4] = cmulf(v[4], p4);
  v[5] = cmulf(v[5], p5); v[6] = cmulf(v[6], p6);
  v[7] = cmulf(v[7], p7);
}

// ======== 256-thread radix-16 machinery (k_khat only; proven) ========
template <int SIGN>
__device__ __forceinline__ void fft16(float2 v[16]) {
  const float sg = (float)SIGN;
  const float C1 = 0.92387953251128674f;
  const float S1 = 0.38268343236508978f;
  const float R2 = 0.70710678118654752f;
  bfly4<SIGN>(v[0], v[4], v[8], v[12]);
  bfly4<SIGN>(v[1], v[5], v[9], v[13]);
  bfly4<SIGN>(v[2], v[6], v[10], v[14]);
  bfly4<SIGN>(v[3], v[7], v[11], v[15]);
  cmul_set(v[5], C1, sg * S1);
  cmul_set(v[6], R2, sg * R2);
  cmul_set(v[7], S1, sg * C1);
  cmul_set(v[9], R2, sg * R2);
  v[10] = make_float2(-sg * v[10].y, sg * v[10].x);
  cmul_set(v[11], -R2, sg * R2);
  cmul_set(v[13], S1, sg * C1);
  cmul_set(v[14], -R2, sg * R2);
  cmul_set(v[15], -C1, -sg * S1);
  float2 w[16];
#pragma unroll
  for (int g = 0; g < 4; ++g) {
    float2 x0 = v[4 * g], x1 = v[4 * g + 1], x2 = v[4 * g + 2],
           x3 = v[4 * g + 3];
    bfly4<SIGN>(x0, x1, x2, x3);
    w[g] = x0; w[g + 4] = x1; w[g + 8] = x2; w[g + 12] = x3;
  }
#pragma unroll
  for (int i = 0; i < 16; ++i) v[i] = w[i];
}

__device__ __forceinline__ void tw_apply(float2 v[16], float ang) {
  float sn, cn;
  __sincosf(ang, &sn, &cn);
  float2 w1 = make_float2(cn, sn), cw = w1;
#pragma unroll
  for (int g = 1; g < 16; ++g) {
    v[g] = cmulf(v[g], cw);
    if (g < 15) cw = cmulf(cw, w1);
  }
}

template <int SIGN>
__device__ void fft4096_regs(float2 v[16], float2* lds, int tid) {
  const int a = tid & 15, g2 = tid >> 4;
  fft16<SIGN>(v);
  tw_apply(v, (float)SIGN * (2.0f * PI_F / 4096.0f) * (float)tid);
  __syncthreads();
#pragma unroll
  for (int g = 0; g < 16; ++g) lds[tid * 17 + g] = v[g];
  __syncthreads();
#pragma unroll
  for (int b = 0; b < 16; ++b) v[b] = lds[a * 17 + b * 272 + g2];
  fft16<SIGN>(v);
  tw_apply(v, (float)SIGN * (2.0f * PI_F / 256.0f) * (float)a);
  __syncthreads();
#pragma unroll
  for (int b = 0; b < 16; ++b) lds[g2 * 17 + b * 273 + a] = v[b];
  __syncthreads();
#pragma unroll
  for (int a2 = 0; a2 < 16; ++a2) v[a2] = lds[g2 * 17 + a * 273 + a2];
  fft16<SIGN>(v);
}

// ---------------- Kernel 1a: Cauchy sums -> atRoots (unchanged) ---------
__global__ __launch_bounds__(256) void k_cauchy(
    const float* __restrict__ Lre, const float* __restrict__ Lim,
    const float* __restrict__ Pri, const float* __restrict__ Bri,
    const float* __restrict__ Cri, const float* __restrict__ lstep,
    float2* __restrict__ atR) {
  __shared__ float4 pA[64];
  __shared__ float4 pB[64];
  __shared__ float2 pL[64];
  const int h = blockIdx.x >> 4;
  const int sub = blockIdx.x & 15;
  const int tid = threadIdx.x;
  if (tid < 64) {
    int base = h * 64 + tid;
    float lr = fminf(Lre[base], -1e-4f);
    float li = Lim[base];
    float pr = Pri[2 * base], pi = Pri[2 * base + 1];
    float br = Bri[2 * base], bi = Bri[2 * base + 1];
    float cr = Cri[2 * base], ci = Cri[2 * base + 1];
    pA[tid] = make_float4(cr * br + ci * bi, cr * bi - ci * br,
                          cr * pr + ci * pi, cr * pi - ci * pr);
    pB[tid] = make_float4(pr * br + pi * bi, pr * bi - pi * br,
                          pr * pr + pi * pi, 0.f);
    pL[tid] = make_float2(lr, li);
  }
  __syncthreads();
  const float istep = expf(-lstep[h]);
  const int m = sub * 256 + tid;
  float sn, cn;
  __sincosf(-(2.0f * PI_F / 4096.0f) * (float)m, &sn, &cn);
  const float trm = 0.5f * (1.0f + cn);
  const float tim = 0.5f * sn;
  const float qrm = (1.0f - cn) * istep;
  const float qim = -sn * istep;
  float S0 = 0.f, S1 = 0.f, S2 = 0.f, S3 = 0.f, S4 = 0.f, S5 = 0.f, S6 = 0.f,
        S7 = 0.f;
#pragma unroll 8
  for (int n = 0; n < 64; ++n) {
    float4 a = pA[n];
    float4 b = pB[n];
    float2 L = pL[n];
    float dr = qrm - (trm * L.x - tim * L.y);
    float di = qim - (trm * L.y + tim * L.x);
    float inv = __builtin_amdgcn_rcpf(dr * dr + di * di);
    float sr = dr * inv, si = -di * inv;
    S0 += a.x * sr - a.y * si;  S1 += a.x * si + a.y * sr;
    S2 += a.z * sr - a.w * si;  S3 += a.z * si + a.w * sr;
    S4 += b.x * sr - b.y * si;  S5 += b.x * si + b.y * sr;
    S6 += b.z * sr;             S7 += b.z * si;
  }
  float tS11r = trm * S6 - tim * S7;
  float tS11i = trm * S7 + tim * S6;
  float denr = 1.0f + tS11r, deni = tS11i;
  float dinv = 1.0f / (denr * denr + deni * deni);
  float P1r = S2 * S4 - S3 * S5;
  float P1i = S2 * S5 + S3 * S4;
  float P2r = trm * P1r - tim * P1i;
  float P2i = trm * P1i + tim * P1r;
  float Qr = (P2r * denr + P2i * deni) * dinv;
  float Qi = (P2i * denr - P2r * deni) * dinv;
  atR[h * 4096 + m] = make_float2(S0 - Qr, S1 - Qi);
}

// ------- Kernel 1b: atRoots -> alpha/beta table (scrambled for conv8) ---
__global__ __launch_bounds__(256, 4) void k_khat(
    const float2* __restrict__ atR, const float* __restrict__ Dp,
    float4* __restrict__ abt) {
  __shared__ float2 lds[4368];
  const int h = blockIdx.x;
  const int tid = threadIdx.x;
  float2 v[16];
#pragma unroll
  for (int c = 0; c < 16; ++c) v[c] = atR[h * 4096 + tid + 256 * c];
  fft4096_regs<1>(v, lds, tid);  // unnormalized inverse -> zK (scrambled)
  const int kb = (tid >> 4) + 16 * (tid & 15);
  float* ldsf = (float*)lds;
  const float s = 1.0f / 4096.0f;
  __syncthreads();
#pragma unroll
  for (int al = 0; al < 16; ++al) ldsf[ad(kb + 256 * al)] = v[al].x * s;
  __syncthreads();
#pragma unroll
  for (int c = 0; c < 8; ++c) {
    int n = tid + 256 * c;
    v[c] = make_float2(ldsf[ad(2 * n)], ldsf[ad(2 * n + 1)]);
  }
#pragma unroll
  for (int c = 8; c < 16; ++c) v[c] = make_float2(0.f, 0.f);
  fft4096_regs<-1>(v, lds, tid);  // forward; scrambled (16-radix layout)
  __syncthreads();
#pragma unroll
  for (int al = 0; al < 16; ++al) lds[ad(kb + 256 * al)] = v[al];
  __syncthreads();
  const float Dh = Dp[h];
#pragma unroll
  for (int c = 0; c < 16; ++c) {
    int k = kb + 256 * c;
    float2 Zk = lds[ad(k)];
    float2 Zm = lds[ad((4096 - k) & 4095)];
    float Er = 0.5f * (Zk.x + Zm.x), Ei = 0.5f * (Zk.y - Zm.y);
    float Or = 0.5f * (Zk.y + Zm.y), Oi = 0.5f * (Zm.x - Zk.x);
    float s_, c_;
    __sincosf(-(PI_F / 4096.0f) * (float)k, &s_, &c_);
    float Gr = c_ * Or - s_ * Oi, Gi = c_ * Oi + s_ * Or;  // G = W*O
    float ar = (Er + Dh + s_ * Gr) * s;
    float ai = (Ei + s_ * Gi) * s;
    float br = (-c_ * Gi) * s;
    float bi = (c_ * Gr) * s;
    // store at conv8's scrambled slot: k = orev(t') + 512*k3 -> slot t'+512k3
    int slot = orev(k & 511) + ((k >> 9) << 9);
    abt[h * 4096 + slot] = make_float4(ar, ai, br, bi);
  }
}

// ---------------- Kernel 2: 512-thread radix-8 FFT convolution ----------
__global__ __launch_bounds__(512, 4) void k_conv8(
    const float* __restrict__ u, const float4* __restrict__ abt,
    float* __restrict__ y) {
  __shared__ float2 lds[4712];
  const int r = blockIdx.x;  // b*128 + h
  const int h = r & 127;
  const int t = threadIdx.x;         // 0..511
  const int t0 = t & 7, t1 = (t >> 3) & 7, t2 = t >> 6;
  // twiddle bases (fwd uses -s, inv uses +s)
  float c_t, s_t, c_6, s_6, c_0, s_0;
  __sincosf((2.0f * PI_F / 4096.0f) * (float)t, &s_t, &c_t);
  __sincosf((2.0f * PI_F / 512.0f) * (float)(t & 63), &s_6, &c_6);
  __sincosf((2.0f * PI_F / 64.0f) * (float)t0, &s_0, &c_0);

  const float2* u2 = (const float2*)(u + (size_t)r * 4096);
  float2 v[8];
#pragma unroll
  for (int c = 0; c < 4; ++c) v[c] = u2[t + 512 * c];
#pragma unroll
  for (int c = 4; c < 8; ++c) v[c] = make_float2(0.f, 0.f);

  // ---- forward: stage A over reg (r-dim) -> k0
  fft8<-1>(v);
  tw8(v, c_t, -s_t);  // * W4096^{t*k0}
  // T1: slot(k0,t0,t1,t2) = 589k0 + 74t0 + 9t1 + t2
#pragma unroll
  for (int g = 0; g < 8; ++g) lds[589 * g + 74 * t0 + 9 * t1 + t2] = v[g];
  __syncthreads();
  // roles now: (k0=t>>6, t1, t0); reg = t2
#pragma unroll
  for (int b = 0; b < 8; ++b) v[b] = lds[589 * t2 + 74 * t0 + 9 * t1 + b];
  fft8<-1>(v);          // over t2 -> k1
  tw8(v, c_6, -s_6);    // * W512^{(t&63)*k1}
  __syncthreads();
  // T2: slot(k0,t0,t1,k1) = 589k0 + 74t0 + 9t1 + k1 ; writer(k0,t1,t0) reg k1
#pragma unroll
  for (int g = 0; g < 8; ++g) lds[589 * t2 + 74 * t0 + 9 * t1 + g] = v[g];
  __syncthreads();
  // roles now: (k0=t>>6, k1=(t>>3)&7, t0); reg = t1
#pragma unroll
  for (int b = 0; b < 8; ++b) v[b] = lds[589 * t2 + 74 * t0 + 9 * b + t1];
  fft8<-1>(v);          // over t1 -> k2
  tw8(v, c_0, -s_0);    // * W64^{t0*k2}
  __syncthreads();
  // T3: slot(k0,k1,t0,k2) = 589k0 + 74k1 + 9t0 + k2 ; writer(k0,k1,t0) reg k2
#pragma unroll
  for (int g = 0; g < 8; ++g) lds[589 * t2 + 74 * t1 + 9 * t0 + g] = v[g];
  __syncthreads();
  // roles now: (k0=t>>6, k1=(t>>3)&7, k2=t&7); reg = t0
#pragma unroll
  for (int b = 0; b < 8; ++b) v[b] = lds[589 * t2 + 74 * t1 + 9 * b + t0];
  fft8<-1>(v);          // over t0 -> k3 ; v[k3] = Z[orev(t) + 512*k3]
  __syncthreads();
  // ---- stage Z (plain layout t' + 512*k3, within lds[0..4096))
#pragma unroll
  for (int g = 0; g < 8; ++g) lds[t + 512 * g] = v[g];
  __syncthreads();
  // ---- spectral multiply
  const int kb = orev(t);
  const float4* __restrict__ abrow = abt + h * 4096;
#pragma unroll
  for (int g = 0; g < 8; ++g) {
    int k = kb + 512 * g;
    int kp = (4096 - k) & 4095;
    float2 Zm = lds[orev(kp & 511) + ((kp >> 9) << 9)];
    float4 ab = abrow[t + 512 * g];  // coalesced (pre-scrambled table)
    float2 Zk = v[g];
    v[g] = make_float2(ab.x * Zk.x - ab.y * Zk.y + ab.z * Zm.x + ab.w * Zm.y,
                       ab.x * Zk.y + ab.y * Zk.x + ab.w * Zm.x - ab.z * Zm.y);
  }
  // ---- inverse (mirror network), scale already folded into alpha/beta
  fft8<1>(v);           // over k3 -> t0'
  __syncthreads();
  // T3inv: writer (k0,k1,k2) reg t0 -> slot(k0,k1,t0,k2)
#pragma unroll
  for (int g = 0; g < 8; ++g) lds[589 * t2 + 74 * t1 + 9 * g + t0] = v[g];
  __syncthreads();
  // reader (k0,k1,t0) reg k2
#pragma unroll
  for (int b = 0; b < 8; ++b) v[b] = lds[589 * t2 + 74 * t1 + 9 * t0 + b];
  tw8(v, c_0, s_0);     // * W64^{+t0*k2}
  fft8<1>(v);           // over k2 -> t1'
  __syncthreads();
  // T2inv: writer (k0,k1,t0) reg t1 -> slot(k0,t0,t1,k1)
#pragma unroll
  for (int g = 0; g < 8; ++g) lds[589 * t2 + 74 * t0 + 9 * g + t1] = v[g];
  __syncthreads();
  // reader (k0,t1,t0) reg k1
#pragma unroll
  for (int b = 0; b < 8; ++b) v[b] = lds[589 * t2 + 74 * t0 + 9 * t1 + b];
  tw8(v, c_6, s_6);     // * W512^{+(t&63)*k1}
  fft8<1>(v);           // over k1 -> t2'
  __syncthreads();
  // T1inv: writer (k0,t1,t0) reg t2 -> slot(k0,t0,t1,t2)
#pragma unroll
  for (int g = 0; g < 8; ++g) lds[589 * t2 + 74 * t0 + 9 * t1 + g] = v[g];
  __syncthreads();
  // reader original t; reg k0
#pragma unroll
  for (int b = 0; b < 8; ++b) v[b] = lds[589 * b + 74 * t0 + 9 * t1 + t2];
  tw8(v, c_t, s_t);     // * W4096^{+t*k0}
  fft8<1>(v);           // over k0 -> r ; v[r] = ypack[t + 512r]
  float2* y2 = (float2*)(y + (size_t)r * 4096);
#pragma unroll
  for (int c = 0; c < 4; ++c) y2[t + 512 * c] = v[c];
}

extern "C" void kernel_launch(void* const* d_in, const int* in_sizes, int n_in,
                              void* d_out, int out_size, void* d_ws,
                              size_t ws_size, hipStream_t stream) {
  (void)in_sizes; (void)n_in; (void)out_size; (void)ws_size;
  const float* u = (const float*)d_in[0];
  const float* Lre = (const float*)d_in[1];
  const float* Lim = (const float*)d_in[2];
  const float* Pri = (const float*)d_in[3];
  const float* Bri = (const float*)d_in[4];
  const float* Cri = (const float*)d_in[5];
  const float* lst = (const float*)d_in[6];
  const float* Dp = (const float*)d_in[7];
  float* y = (float*)d_out;
  float2* atR = (float2*)d_ws;                                     // 4 MiB
  float4* abt = (float4*)((char*)d_ws + (size_t)4 * 1024 * 1024);  // 8 MiB

  k_cauchy<<<2048, 256, 0, stream>>>(Lre, Lim, Pri, Bri, Cri, lst, atR);
  k_khat<<<128, 256, 0, stream>>>(atR, Dp, abt);
  k_conv8<<<2048, 512, 0, stream>>>(u, abt, y);
}

// Round 8
// 156.535 us; speedup vs baseline: 1.0240x; 1.0240x over previous
//
#include <hip/hip_runtime.h>
#include <hip/hip_bf16.h>

// S4 layer: y = irfft( rfft(pad(u)) * (rfft(pad(K)) + D) )[:L]
// B=16, H=128, L=4096, N=64. All fp32.
// k_conv2 (this round): DUAL-ROW radix-16 FFT4096. Each 256-thread block
// carries TWO rows (b,h) and (b+8,h) as va[16]/vb[16] through one shared
// barrier network: barriers per row halve (5 vs 11), twiddle chains and
// LDS addresses computed once for both rows, alpha/beta float4 loaded once
// per bin for both rows. Two 4096-float2 XOR-swizzled buffers = exactly
// 64 KB static LDS (2 blocks/CU); ILP (2 dependent chains/thread) replaces
// TLP that R3/R6/R7 showed doesn't help (barrier-phased structure).
// launch_bounds (256,1): never force VGPR below natural (R4/R5: forced
// caps spill v[16] to scratch; watch WRITE_SIZE ~33MB as no-spill signal).
// ws: [0,4MiB) atR 128x4096 float2 ; [4MiB,12MiB) abt 128x4096 float4
//   (abt scrambled in radix-16 order: slot tid+256c <-> k=kb+256c).

#define PI_F 3.14159265358979323846f

__device__ __forceinline__ float2 cmulf(float2 a, float2 b) {
  return make_float2(a.x * b.x - a.y * b.y, a.x * b.y + a.y * b.x);
}
__device__ __forceinline__ void cmul_set(float2& v, float wr, float wi) {
  v = make_float2(v.x * wr - v.y * wi, v.x * wi + v.y * wr);
}
__device__ __forceinline__ int ad(int k) { return k + (k >> 4); }   // pad-17
__device__ __forceinline__ int sw16(int j) { return j ^ ((j >> 4) & 15); }

template <int SIGN>
__device__ __forceinline__ void bfly4(float2& a, float2& b, float2& c,
                                      float2& d) {
  float t0x = a.x + c.x, t0y = a.y + c.y;
  float t1x = a.x - c.x, t1y = a.y - c.y;
  float t2x = b.x + d.x, t2y = b.y + d.y;
  float t3x = b.x - d.x, t3y = b.y - d.y;
  a = make_float2(t0x + t2x, t0y + t2y);
  c = make_float2(t0x - t2x, t0y - t2y);
  if (SIGN < 0) {
    b = make_float2(t1x + t3y, t1y - t3x);
    d = make_float2(t1x - t3y, t1y + t3x);
  } else {
    b = make_float2(t1x - t3y, t1y + t3x);
    d = make_float2(t1x + t3y, t1y - t3x);
  }
}

// in-register 16-point DFT, natural in / natural out, constant twiddles.
template <int SIGN>
__device__ __forceinline__ void fft16(float2 v[16]) {
  const float sg = (float)SIGN;
  const float C1 = 0.92387953251128674f;
  const float S1 = 0.38268343236508978f;
  const float R2 = 0.70710678118654752f;
  bfly4<SIGN>(v[0], v[4], v[8], v[12]);
  bfly4<SIGN>(v[1], v[5], v[9], v[13]);
  bfly4<SIGN>(v[2], v[6], v[10], v[14]);
  bfly4<SIGN>(v[3], v[7], v[11], v[15]);
  cmul_set(v[5], C1, sg * S1);
  cmul_set(v[6], R2, sg * R2);
  cmul_set(v[7], S1, sg * C1);
  cmul_set(v[9], R2, sg * R2);
  v[10] = make_float2(-sg * v[10].y, sg * v[10].x);
  cmul_set(v[11], -R2, sg * R2);
  cmul_set(v[13], S1, sg * C1);
  cmul_set(v[14], -R2, sg * R2);
  cmul_set(v[15], -C1, -sg * S1);
  float2 w[16];
#pragma unroll
  for (int g = 0; g < 4; ++g) {
    float2 x0 = v[4 * g], x1 = v[4 * g + 1], x2 = v[4 * g + 2],
           x3 = v[4 * g + 3];
    bfly4<SIGN>(x0, x1, x2, x3);
    w[g] = x0; w[g + 4] = x1; w[g + 8] = x2; w[g + 12] = x3;
  }
#pragma unroll
  for (int i = 0; i < 16; ++i) v[i] = w[i];
}

__device__ __forceinline__ void tw_apply(float2 v[16], float ang) {
  float sn, cn;
  __sincosf(ang, &sn, &cn);
  float2 w1 = make_float2(cn, sn), cw = w1;
#pragma unroll
  for (int g = 1; g < 16; ++g) {
    v[g] = cmulf(v[g], cw);
    if (g < 15) cw = cmulf(cw, w1);
  }
}

// shared-chain twiddle for two rows
__device__ __forceinline__ void tw_apply2(float2 va[16], float2 vb[16],
                                          float ang) {
  float sn, cn;
  __sincosf(ang, &sn, &cn);
  float2 w1 = make_float2(cn, sn), cw = w1;
#pragma unroll
  for (int g = 1; g < 16; ++g) {
    va[g] = cmulf(va[g], cw);
    vb[g] = cmulf(vb[g], cw);
    if (g < 15) cw = cmulf(cw, w1);
  }
}

// ======== pad-17 single-row machinery (k_khat only; proven) ========
template <int SIGN>
__device__ void fft4096_regs(float2 v[16], float2* lds, int tid) {
  const int a = tid & 15, g2 = tid >> 4;
  fft16<SIGN>(v);
  tw_apply(v, (float)SIGN * (2.0f * PI_F / 4096.0f) * (float)tid);
  __syncthreads();
#pragma unroll
  for (int g = 0; g < 16; ++g) lds[tid * 17 + g] = v[g];
  __syncthreads();
#pragma unroll
  for (int b = 0; b < 16; ++b) v[b] = lds[a * 17 + b * 272 + g2];
  fft16<SIGN>(v);
  tw_apply(v, (float)SIGN * (2.0f * PI_F / 256.0f) * (float)a);
  __syncthreads();
#pragma unroll
  for (int b = 0; b < 16; ++b) lds[g2 * 17 + b * 273 + a] = v[b];
  __syncthreads();
#pragma unroll
  for (int a2 = 0; a2 < 16; ++a2) v[a2] = lds[g2 * 17 + a * 273 + a2];
  fft16<SIGN>(v);
  // no trailing barrier; callers must __syncthreads before reusing lds.
}

// ======== dual-row swizzled forward: natural -> scrambled ========
template <int SIGN>
__device__ void fft4096_x2(float2 va[16], float2 vb[16], float2* A, float2* B,
                           int tid) {
  const int a = tid & 15, g2 = tid >> 4;
  fft16<SIGN>(va);
  fft16<SIGN>(vb);
  tw_apply2(va, vb, (float)SIGN * (2.0f * PI_F / 4096.0f) * (float)tid);
  __syncthreads();
#pragma unroll
  for (int g = 0; g < 16; ++g) {
    int s = (tid << 4) | (g ^ a);
    A[s] = va[g];
    B[s] = vb[g];
  }
  __syncthreads();
#pragma unroll
  for (int b = 0; b < 16; ++b) {
    int s = ((a + 16 * b) << 4) | (g2 ^ a);
    va[b] = A[s];
    vb[b] = B[s];
  }
  fft16<SIGN>(va);
  fft16<SIGN>(vb);
  tw_apply2(va, vb, (float)SIGN * (2.0f * PI_F / 256.0f) * (float)a);
  __syncthreads();
#pragma unroll
  for (int b = 0; b < 16; ++b) {
    int s = (g2 << 8) | (b << 4) | (a ^ b);
    A[s] = va[b];
    B[s] = vb[b];
  }
  __syncthreads();
#pragma unroll
  for (int a2 = 0; a2 < 16; ++a2) {
    int s = (g2 << 8) | (a << 4) | (a2 ^ a);
    va[a2] = A[s];
    vb[a2] = B[s];
  }
  fft16<SIGN>(va);
  fft16<SIGN>(vb);
  // no trailing barrier.
}

// ======== dual-row swizzled inverse: scrambled -> natural ========
template <int SIGN>
__device__ void fft4096_x2_s2n(float2 va[16], float2 vb[16], float2* A,
                               float2* B, int tid) {
  const int a = tid & 15, g2 = tid >> 4;
  fft16<SIGN>(va);
  fft16<SIGN>(vb);
  __syncthreads();  // guard callers' prior lds reads
#pragma unroll
  for (int r = 0; r < 16; ++r) {
    int s = (g2 << 8) | (a << 4) | (r ^ a);
    A[s] = va[r];
    B[s] = vb[r];
  }
  __syncthreads();
#pragma unroll
  for (int b = 0; b < 16; ++b) {
    int s = (g2 << 8) | (b << 4) | (a ^ b);
    va[b] = A[s];
    vb[b] = B[s];
  }
  tw_apply2(va, vb, (float)SIGN * (2.0f * PI_F / 256.0f) * (float)a);
  fft16<SIGN>(va);
  fft16<SIGN>(vb);
  __syncthreads();
#pragma unroll
  for (int r = 0; r < 16; ++r) {
    int s = ((16 * r + a) << 4) | (g2 ^ a);
    A[s] = va[r];
    B[s] = vb[r];
  }
  __syncthreads();
#pragma unroll
  for (int g = 0; g < 16; ++g) {
    int s = (tid << 4) | (g ^ a);
    va[g] = A[s];
    vb[g] = B[s];
  }
  tw_apply2(va, vb, (float)SIGN * (2.0f * PI_F / 4096.0f) * (float)tid);
  fft16<SIGN>(va);
  fft16<SIGN>(vb);
}

// ---------------- Kernel 1a: Cauchy sums -> atRoots (unchanged) ---------
__global__ __launch_bounds__(256) void k_cauchy(
    const float* __restrict__ Lre, const float* __restrict__ Lim,
    const float* __restrict__ Pri, const float* __restrict__ Bri,
    const float* __restrict__ Cri, const float* __restrict__ lstep,
    float2* __restrict__ atR) {
  __shared__ float4 pA[64];
  __shared__ float4 pB[64];
  __shared__ float2 pL[64];
  const int h = blockIdx.x >> 4;
  const int sub = blockIdx.x & 15;
  const int tid = threadIdx.x;
  if (tid < 64) {
    int base = h * 64 + tid;
    float lr = fminf(Lre[base], -1e-4f);
    float li = Lim[base];
    float pr = Pri[2 * base], pi = Pri[2 * base + 1];
    float br = Bri[2 * base], bi = Bri[2 * base + 1];
    float cr = Cri[2 * base], ci = Cri[2 * base + 1];
    pA[tid] = make_float4(cr * br + ci * bi, cr * bi - ci * br,
                          cr * pr + ci * pi, cr * pi - ci * pr);
    pB[tid] = make_float4(pr * br + pi * bi, pr * bi - pi * br,
                          pr * pr + pi * pi, 0.f);
    pL[tid] = make_float2(lr, li);
  }
  __syncthreads();
  const float istep = expf(-lstep[h]);
  const int m = sub * 256 + tid;
  float sn, cn;
  __sincosf(-(2.0f * PI_F / 4096.0f) * (float)m, &sn, &cn);
  const float trm = 0.5f * (1.0f + cn);
  const float tim = 0.5f * sn;
  const float qrm = (1.0f - cn) * istep;
  const float qim = -sn * istep;
  float S0 = 0.f, S1 = 0.f, S2 = 0.f, S3 = 0.f, S4 = 0.f, S5 = 0.f, S6 = 0.f,
        S7 = 0.f;
#pragma unroll 8
  for (int n = 0; n < 64; ++n) {
    float4 a = pA[n];
    float4 b = pB[n];
    float2 L = pL[n];
    float dr = qrm - (trm * L.x - tim * L.y);
    float di = qim - (trm * L.y + tim * L.x);
    float inv = __builtin_amdgcn_rcpf(dr * dr + di * di);
    float sr = dr * inv, si = -di * inv;
    S0 += a.x * sr - a.y * si;  S1 += a.x * si + a.y * sr;
    S2 += a.z * sr - a.w * si;  S3 += a.z * si + a.w * sr;
    S4 += b.x * sr - b.y * si;  S5 += b.x * si + b.y * sr;
    S6 += b.z * sr;             S7 += b.z * si;
  }
  float tS11r = trm * S6 - tim * S7;
  float tS11i = trm * S7 + tim * S6;
  float denr = 1.0f + tS11r, deni = tS11i;
  float dinv = 1.0f / (denr * denr + deni * deni);
  float P1r = S2 * S4 - S3 * S5;
  float P1i = S2 * S5 + S3 * S4;
  float P2r = trm * P1r - tim * P1i;
  float P2i = trm * P1i + tim * P1r;
  float Qr = (P2r * denr + P2i * deni) * dinv;
  float Qi = (P2i * denr - P2r * deni) * dinv;
  atR[h * 4096 + m] = make_float2(S0 - Qr, S1 - Qi);
}

// ------- Kernel 1b: atRoots -> alpha/beta table (radix-16 scramble) -----
__global__ __launch_bounds__(256, 4) void k_khat(
    const float2* __restrict__ atR, const float* __restrict__ Dp,
    float4* __restrict__ abt) {
  __shared__ float2 lds[4368];
  const int h = blockIdx.x;
  const int tid = threadIdx.x;
  float2 v[16];
#pragma unroll
  for (int c = 0; c < 16; ++c) v[c] = atR[h * 4096 + tid + 256 * c];
  fft4096_regs<1>(v, lds, tid);  // unnormalized inverse -> zK (scrambled)
  const int kb = (tid >> 4) + 16 * (tid & 15);
  float* ldsf = (float*)lds;
  const float s = 1.0f / 4096.0f;
  __syncthreads();
#pragma unroll
  for (int al = 0; al < 16; ++al) ldsf[ad(kb + 256 * al)] = v[al].x * s;
  __syncthreads();
#pragma unroll
  for (int c = 0; c < 8; ++c) {
    int n = tid + 256 * c;
    v[c] = make_float2(ldsf[ad(2 * n)], ldsf[ad(2 * n + 1)]);
  }
#pragma unroll
  for (int c = 8; c < 16; ++c) v[c] = make_float2(0.f, 0.f);
  fft4096_regs<-1>(v, lds, tid);  // forward; scrambled
  __syncthreads();
#pragma unroll
  for (int al = 0; al < 16; ++al) lds[ad(kb + 256 * al)] = v[al];
  __syncthreads();
  const float Dh = Dp[h];
#pragma unroll
  for (int c = 0; c < 16; ++c) {
    int k = kb + 256 * c;
    float2 Zk = lds[ad(k)];
    float2 Zm = lds[ad((4096 - k) & 4095)];
    float Er = 0.5f * (Zk.x + Zm.x), Ei = 0.5f * (Zk.y - Zm.y);
    float Or = 0.5f * (Zk.y + Zm.y), Oi = 0.5f * (Zm.x - Zk.x);
    float s_, c_;
    __sincosf(-(PI_F / 4096.0f) * (float)k, &s_, &c_);
    float Gr = c_ * Or - s_ * Oi, Gi = c_ * Oi + s_ * Or;  // G = W*O
    float ar = (Er + Dh + s_ * Gr) * s;
    float ai = (Ei + s_ * Gi) * s;
    float br = (-c_ * Gi) * s;
    float bi = (c_ * Gr) * s;
    abt[h * 4096 + tid + 256 * c] = make_float4(ar, ai, br, bi);  // scrambled
  }
}

// ---------------- Kernel 2: dual-row FFT convolution ----------------
// 1024 blocks: block i does rows i and i+1024 (same h, batches b and b+8).
__global__ __launch_bounds__(256, 1) void k_conv2(
    const float* __restrict__ u, const float4* __restrict__ abt,
    float* __restrict__ y) {
  __shared__ float2 lds[8192];  // 64 KB: two 32 KB row buffers
  float2* A = lds;
  float2* B = lds + 4096;
  const int i = blockIdx.x;  // 0..1023
  const int h = i & 127;
  const int tid = threadIdx.x;
  const float2* uA = (const float2*)(u + (size_t)i * 4096);
  const float2* uB = (const float2*)(u + (size_t)(i + 1024) * 4096);
  float2 va[16], vb[16];
#pragma unroll
  for (int c = 0; c < 8; ++c) {
    va[c] = uA[tid + 256 * c];
    vb[c] = uB[tid + 256 * c];
  }
#pragma unroll
  for (int c = 8; c < 16; ++c) {
    va[c] = make_float2(0.f, 0.f);
    vb[c] = make_float2(0.f, 0.f);
  }
  fft4096_x2<-1>(va, vb, A, B, tid);  // forward; v[al]=Z[kb+256al]
  const int kb = (tid >> 4) + 16 * (tid & 15);
  __syncthreads();  // lagging T2 reads done before overwrite
#pragma unroll
  for (int al = 0; al < 16; ++al) {
    int s = sw16(kb + 256 * al);
    A[s] = va[al];
    B[s] = vb[al];
  }
  __syncthreads();
  const float4* __restrict__ abrow = abt + h * 4096;
#pragma unroll
  for (int al = 0; al < 16; ++al) {
    int k = kb + 256 * al;
    int sp = sw16((4096 - k) & 4095);
    float4 ab = abrow[tid + 256 * al];  // one load serves both rows
    float2 Zma = A[sp];
    float2 Zmb = B[sp];
    float2 Za = va[al];
    float2 Zb = vb[al];
    va[al] =
        make_float2(ab.x * Za.x - ab.y * Za.y + ab.z * Zma.x + ab.w * Zma.y,
                    ab.x * Za.y + ab.y * Za.x + ab.w * Zma.x - ab.z * Zma.y);
    vb[al] =
        make_float2(ab.x * Zb.x - ab.y * Zb.y + ab.z * Zmb.x + ab.w * Zmb.y,
                    ab.x * Zb.y + ab.y * Zb.x + ab.w * Zmb.x - ab.z * Zmb.y);
  }
  fft4096_x2_s2n<1>(va, vb, A, B, tid);  // inverse (scale folded in ab)
  float2* yA = (float2*)(y + (size_t)i * 4096);
  float2* yB = (float2*)(y + (size_t)(i + 1024) * 4096);
#pragma unroll
  for (int c = 0; c < 8; ++c) {
    yA[tid + 256 * c] = va[c];
    yB[tid + 256 * c] = vb[c];
  }
}

extern "C" void kernel_launch(void* const* d_in, const int* in_sizes, int n_in,
                              void* d_out, int out_size, void* d_ws,
                              size_t ws_size, hipStream_t stream) {
  (void)in_sizes; (void)n_in; (void)out_size; (void)ws_size;
  const float* u = (const float*)d_in[0];
  const float* Lre = (const float*)d_in[1];
  const float* Lim = (const float*)d_in[2];
  const float* Pri = (const float*)d_in[3];
  const float* Bri = (const float*)d_in[4];
  const float* Cri = (const float*)d_in[5];
  const float* lst = (const float*)d_in[6];
  const float* Dp = (const float*)d_in[7];
  float* y = (float*)d_out;
  float2* atR = (float2*)d_ws;                                     // 4 MiB
  float4* abt = (float4*)((char*)d_ws + (size_t)4 * 1024 * 1024);  // 8 MiB

  k_cauchy<<<2048, 256, 0, stream>>>(Lre, Lim, Pri, Bri, Cri, lst, atR);
  k_khat<<<128, 256, 0, stream>>>(atR, Dp, abt);
  k_conv2<<<1024, 256, 0, stream>>>(u, abt, y);
}